// Round 7
// baseline (341.406 us; speedup 1.0000x reference)
//
#include <hip/hip_runtime.h>

#define TT   512
#define CH   128
#define HWP  784        // 28*28
#define NSEG 8
#define NOUT 51380224   // 512*128*784

typedef short bf16x8  __attribute__((ext_vector_type(8)));
typedef float f32x4   __attribute__((ext_vector_type(4)));
typedef float f32x16  __attribute__((ext_vector_type(16)));
typedef int   i32x4   __attribute__((ext_vector_type(4)));
typedef unsigned short u16x4 __attribute__((ext_vector_type(4)));
typedef unsigned short u16x8 __attribute__((ext_vector_type(8)));

__device__ inline unsigned short f2bf(float f) {
    unsigned u = __builtin_bit_cast(unsigned, f);
    u += 0x7fffu + ((u >> 16) & 1u);          // RNE
    return (unsigned short)(u >> 16);
}

__device__ inline void gld_lds16(const void* g, void* l) {
    __builtin_amdgcn_global_load_lds(
        (const __attribute__((address_space(1))) void*)g,
        (__attribute__((address_space(3))) void*)l, 16, 0, 0);
}

#define MFMA32(A, B, C) __builtin_amdgcn_mfma_f32_32x32x16_bf16(A, B, C, 0, 0, 0)

// ---------------------------------------------------------------------------
// Spatial weight repack for 32x32x16 MFMA, frag-major:
// frag f = tap*8+ks, block m: lane l = kgrp*32 + (co&31), elem e: ci = ks*16+kgrp*8+e
// dst = ((f*4 + m)*64 + l)*8 + e
// ---------------------------------------------------------------------------
__global__ void repack_wsp(const float* __restrict__ w, short* __restrict__ wA) {
    int s = blockIdx.x * 256 + threadIdx.x;
    if (s >= 128 * 128 * 9) return;
    int co = s / 1152, r = s % 1152, ci = r / 9, kh = (r % 9) / 3, kw = r % 3;
    int tap = kh * 3 + kw;
    int m = co >> 5, row = co & 31;
    int ks = ci >> 4, kgrp = (ci >> 3) & 1, e = ci & 7;
    int lane = kgrp * 32 + row;
    int dst = (((tap * 8 + ks) * 4 + m) * 64 + lane) * 8 + e;
    wA[dst] = (short)f2bf(w[s]);
}

// ---------------------------------------------------------------------------
// Temporal weight repack (identity ci order, 16x16x32 frag-major):
// wAt[tap][o>>4][i>>5][(i>>3)&3][o&15][i&7]
// ---------------------------------------------------------------------------
__global__ void repack_wt2(const float* __restrict__ w, short* __restrict__ wAt) {
    int s = blockIdx.x * 256 + threadIdx.x;
    if (s >= 128 * 128 * 3) return;
    int o = s / 384, r = s % 384, i = r / 3, tap = r % 3;
    int dst = tap * 16384 + (o >> 4) * 2048 + (i >> 5) * 512 +
              ((i >> 3) & 3) * 128 + (o & 15) * 8 + (i & 7);
    wAt[dst] = (short)f2bf(w[s]);
}

// ---------------------------------------------------------------------------
// Spatial 3x3 conv via mfma_f32_32x32x16_bf16. grid (8, 512), block 256.
// Block: (rowgroup rg, half hf) = 4 px-tiles of 32; 7-row LDS window
// [7][30 st][128 ci] bf16, slot swizzle slot' = slot ^ (st&15).
// Waves: ch(2 co-halves) x pg(2): wave = 64 co x 64 px (2 tiles), m2nf2.
// Depth-2 software pipeline on BOTH A (global) and B (LDS).
// Epilogue: acc -> LDS bounce -> 128B-contiguous u16x8 stores.
// ---------------------------------------------------------------------------
__global__ __launch_bounds__(256, 3) void spatial_mfma(
    const float* __restrict__ x, const short* __restrict__ wA,
    const float* __restrict__ b_sp, unsigned short* __restrict__ yT)
{
    __shared__ __align__(16) short xs[7 * 30 * 128];   // 53760 B
    char* xsb = (char*)xs;
    const int t = blockIdx.y;
    const int rg = blockIdx.x >> 1, hf = blockIdx.x & 1;
    const int r0 = rg * 8;
    const int rows = (28 - r0 < 8) ? (28 - r0) : 8;
    const int pxcnt = rows * 28;
    if (hf * 128 >= pxcnt) return;           // rg3/hf1: nothing to do
    const int tid = threadIdx.x;
    const int wstart = r0 + hf * 4 - 1;

    // ---- stage 7-row window (+ zero pad cols), conflict-free writes ----
    for (int u = tid; u < 4032; u += 256) {
        if (u < 3136) {
            int cp = u & 63, q = u >> 6;     // q 0..48
            int rl = q / 7, g = q % 7;
            int rr = wstart + rl;
            float4 f0 = make_float4(0.f, 0.f, 0.f, 0.f), f1 = f0;
            if (rr >= 0 && rr < 28) {
                const float* px0 = &x[((size_t)(t * CH + 2 * cp)) * HWP + rr * 28 + g * 4];
                f0 = *(const float4*)px0;
                f1 = *(const float4*)(px0 + HWP);
            }
            float a0[4] = {f0.x, f0.y, f0.z, f0.w}, a1[4] = {f1.x, f1.y, f1.z, f1.w};
            int stb = rl * 30 + g * 4 + 1;
#pragma unroll
            for (int j = 0; j < 4; ++j) {
                int st = stb + j;
                unsigned val = (unsigned)f2bf(a0[j]) | ((unsigned)f2bf(a1[j]) << 16);
                int addr = (st << 8) | (((cp >> 2) ^ (st & 15)) << 4) | ((cp & 3) << 2);
                *(unsigned*)(xsb + addr) = val;
            }
        } else {
            int v = u - 3136;                // 0..895
            int cp = v & 63, k = v >> 6;     // k 0..13
            int st = (k >> 1) * 30 + (k & 1) * 29;
            int addr = (st << 8) | (((cp >> 2) ^ (st & 15)) << 4) | ((cp & 3) << 2);
            *(unsigned*)(xsb + addr) = 0u;
        }
    }
    __syncthreads();

    const int wid = tid >> 6, l = tid & 63;
    const int l31 = l & 31, bb5 = l >> 5;
    const int ch = wid & 1, pg = wid >> 1;
    const int ch2 = ch * 2;
    const int tI0 = hf * 4 + pg * 2, tI1 = tI0 + 1;
    const int p0 = tI0 * 32 + l31, p1 = tI1 * 32 + l31;
    const int pc0 = (p0 < pxcnt) ? p0 : hf * 128;     // clamp invalid lanes
    const int pc1 = (p1 < pxcnt) ? p1 : hf * 128;
    const int st0_0 = (pc0 / 28 - hf * 4 + 1) * 30 + pc0 % 28 + 1;
    const int st0_1 = (pc1 / 28 - hf * 4 + 1) * 30 + pc1 % 28 + 1;

    f32x16 zz = {};
    f32x16 acc00 = zz, acc10 = zz, acc01 = zz, acc11 = zz;  // [m][tile]

    const bf16x8* wv = (const bf16x8*)wA;

    auto ldB = [&](int it, int s0) -> i32x4 {
        int tap = it >> 3;
        int off = (tap / 3 - 1) * 30 + (tap % 3) - 1;
        int stv = s0 + off;
        int addr = (stv << 8) | ((((it & 7) * 2 + bb5) ^ (stv & 15)) << 4);
        return *(const i32x4*)(xsb + addr);
    };

    // ---- depth-2 pipeline prologue ----
    i32x4 B0a = ldB(0, st0_0), B0b = ldB(0, st0_1);
    i32x4 B1a = ldB(1, st0_0), B1b = ldB(1, st0_1);
    bf16x8 A0a = wv[(0 * 4 + ch2) * 64 + l], A0b = wv[(0 * 4 + ch2 + 1) * 64 + l];
    bf16x8 A1a = wv[(1 * 4 + ch2) * 64 + l], A1b = wv[(1 * 4 + ch2 + 1) * 64 + l];

#pragma unroll
    for (int it = 0; it < 72; ++it) {
        int nx = (it + 2 < 72) ? (it + 2) : 70;       // dup-read tail, harmless
        i32x4 nBa = ldB(nx, st0_0), nBb = ldB(nx, st0_1);
        bf16x8 nAa = wv[(nx * 4 + ch2) * 64 + l];
        bf16x8 nAb = wv[(nx * 4 + ch2 + 1) * 64 + l];

        bf16x8 fa = __builtin_bit_cast(bf16x8, B0a);
        bf16x8 fb = __builtin_bit_cast(bf16x8, B0b);
        __builtin_amdgcn_s_setprio(1);
        acc00 = MFMA32(A0a, fa, acc00);
        acc10 = MFMA32(A0b, fa, acc10);
        acc01 = MFMA32(A0a, fb, acc01);
        acc11 = MFMA32(A0b, fb, acc11);
        __builtin_amdgcn_s_setprio(0);

        B0a = B1a; B0b = B1b; B1a = nBa; B1b = nBb;   // SSA renames under unroll
        A0a = A1a; A0b = A1b; A1a = nAa; A1b = nAb;
    }

    // ---- epilogue: window is dead; bounce acc through LDS for contiguity ----
    __syncthreads();                          // all waves done reading window
    const int wbase = wid * 8704;             // 2 tiles x 32 px x 136 B
#pragma unroll
    for (int mi = 0; mi < 2; ++mi) {
        f32x16 aT0 = mi ? acc10 : acc00;
        f32x16 aT1 = mi ? acc11 : acc01;
#pragma unroll
        for (int r2 = 0; r2 < 4; ++r2) {
            int cb = (ch2 + mi) * 32 + 8 * r2 + 4 * bb5;
            float4 bs = *(const float4*)&b_sp[cb];
            float bsa[4] = {bs.x, bs.y, bs.z, bs.w};
            u16x4 k0, k1;
#pragma unroll
            for (int q = 0; q < 4; ++q) {
                k0[q] = f2bf(aT0[r2 * 4 + q] + bsa[q]);
                k1[q] = f2bf(aT1[r2 * 4 + q] + bsa[q]);
            }
            int co_off = (mi * 32 + 8 * r2 + 4 * bb5) * 2;   // within 64-ch half
            *(u16x4*)(xsb + wbase + l31 * 136 + co_off) = k0;
            *(u16x4*)(xsb + wbase + 4352 + l31 * 136 + co_off) = k1;
        }
    }
    // wave-private region: compiler inserts lgkmcnt before dependent reads
#pragma unroll
    for (int tt2 = 0; tt2 < 2; ++tt2) {
        int tI = tt2 ? tI1 : tI0;
#pragma unroll
        for (int j = 0; j < 4; ++j) {
            int idx = j * 64 + l;
            int px = idx >> 3, sub = idx & 7;
            u16x8 v = *(const u16x8*)(xsb + wbase + tt2 * 4352 + px * 136 + sub * 16);
            int p = tI * 32 + px;
            if (p < pxcnt) {
                char* dst = (char*)yT + ((size_t)t * HWP + r0 * 28 + p) * 256 +
                            ch * 128 + sub * 16;
                *(u16x8*)dst = v;
            }
        }
    }
}

// ---------------------------------------------------------------------------
// Ragged temporal conv: 4-wave blocks, async LDS-staged B, double-buffered.
// grid (7, 512), block 256. (unchanged — at HBM roofline)
// ---------------------------------------------------------------------------
__global__ __launch_bounds__(256, 4) void temporal_mfma(
    const unsigned short* __restrict__ yT, const short* __restrict__ wAt,
    const float* __restrict__ b_t, const float* __restrict__ alpha,
    const float* __restrict__ x, const int* __restrict__ vid_lens,
    float* __restrict__ out)
{
    __shared__ __align__(16) char ldsT[29696];   // 2x14336 stage | 4x7424 epi

    const int chunk = blockIdx.x, t = blockIdx.y;
    const int tid = threadIdx.x, wid = tid >> 6, l = tid & 63;
    const int l15 = l & 15, kgrp = l >> 4;
    const int sx = l15 & 7;

    bool isS = false, isE = false;
    {
        int cum = 0;
        for (int s = 0; s < NSEG; ++s) {
            if (t == cum) isS = true;
            cum += vid_lens[s];
            if (t == cum - 1) isE = true;
        }
    }
    const bool tapAct[3] = {!isS, true, !isE};

    auto stage = [&](int s) {
        int tap = s >> 1, kp = s & 1;
        if (!tapAct[tap]) return;
        int tp = t + tap - 1;
        const char* yb = (const char*)yT + (size_t)tp * HWP * 256;
        char* buf = ldsT + (s & 1) * 14336;
#pragma unroll
        for (int r = 0; r < 4; ++r) {
            int c = r * 256 + wid * 64 + l;
            if (r < 3 || wid < 2) {                    // c < 896, wave-uniform
                int px = c >> 3, sp = c & 7;
                int ssrc = sp ^ (px & 7);
                const char* g = yb + ((size_t)(chunk * 112 + px)) * 256 + kp * 128 + ssrc * 16;
                char* ldst = buf + (r * 256 + wid * 64) * 16;
                gld_lds16(g, ldst);
            }
        }
    };

    f32x4 acc[2][7];
#pragma unroll
    for (int m = 0; m < 2; ++m)
#pragma unroll
        for (int n = 0; n < 7; ++n) acc[m][n] = (f32x4){0.f, 0.f, 0.f, 0.f};

    const bf16x8* wAv = (const bf16x8*)wAt;

    stage(0);
    __syncthreads();

    for (int s = 0; s < 6; ++s) {
        if (s < 5) stage(s + 1);
        int tap = s >> 1, kp = s & 1;
        if (tapAct[tap]) {
            const char* buf = ldsT + (s & 1) * 14336;
            bf16x8 a[2][2];
#pragma unroll
            for (int m = 0; m < 2; ++m)
#pragma unroll
                for (int k1 = 0; k1 < 2; ++k1)
                    a[m][k1] = wAv[((tap * 8 + wid * 2 + m) * 4 + kp * 2 + k1) * 64 + l];
            __builtin_amdgcn_s_setprio(1);
#pragma unroll
            for (int k1 = 0; k1 < 2; ++k1) {
#pragma unroll
                for (int nf = 0; nf < 7; ++nf) {
                    int addr = (nf * 16 + l15) * 128 + ((k1 * 4 + kgrp) ^ sx) * 16;
                    i32x4 bi = *(const i32x4*)(buf + addr);
                    bf16x8 b = __builtin_bit_cast(bf16x8, bi);
                    acc[0][nf] = __builtin_amdgcn_mfma_f32_16x16x32_bf16(a[0][k1], b, acc[0][nf], 0, 0, 0);
                    acc[1][nf] = __builtin_amdgcn_mfma_f32_16x16x32_bf16(a[1][k1], b, acc[1][nf], 0, 0, 0);
                }
            }
            __builtin_amdgcn_s_setprio(0);
        }
        __syncthreads();
    }

    // ---- epilogue: LDS transpose -> coalesced bias/PReLU/residual/store ----
    float* fl = (float*)ldsT;
    const int wbase = wid * 1856;            // 16 co x 116 px-stride floats
#pragma unroll
    for (int m = 0; m < 2; ++m) {
#pragma unroll
        for (int nf = 0; nf < 7; ++nf)
#pragma unroll
            for (int rr = 0; rr < 4; ++rr)
                fl[wbase + (kgrp * 4 + rr) * 116 + nf * 16 + l15] = acc[m][nf][rr];
#pragma unroll
        for (int j = 0; j < 7; ++j) {
            int idx = j * 64 + l;
            int co_r = idx / 28, q = idx % 28;
            f32x4 v4 = *(const f32x4*)&fl[wbase + co_r * 116 + q * 4];
            int co_g = wid * 32 + m * 16 + co_r;
            float bt = b_t[co_g], al = alpha[co_g];
            size_t gi = ((size_t)(t * CH + co_g)) * HWP + chunk * 112 + q * 4;
            float4 xv = *(const float4*)&x[gi];
            float xr[4] = {xv.x, xv.y, xv.z, xv.w};
            float rrv[4];
#pragma unroll
            for (int e = 0; e < 4; ++e) {
                float v = v4[e] + bt;
                v = (v >= 0.f) ? v : al * v;
                rrv[e] = v + xr[e];
            }
            *(float4*)&out[gi] = make_float4(rrv[0], rrv[1], rrv[2], rrv[3]);
        }
        __syncthreads();   // all waves done with region before m=1 reuse
    }
}

// ---------------------------------------------------------------------------
__global__ void write_lens(const int* __restrict__ vid_lens, float* __restrict__ out) {
    int i = threadIdx.x;
    if (i < NSEG) out[NOUT + i] = (float)vid_lens[i];
}

// ---------------------------------------------------------------------------
extern "C" void kernel_launch(void* const* d_in, const int* in_sizes, int n_in,
                              void* d_out, int out_size, void* d_ws, size_t ws_size,
                              hipStream_t stream) {
    const float* x        = (const float*)d_in[0];
    const int*   vid_lens = (const int*)d_in[1];
    const float* w_sp     = (const float*)d_in[2];
    const float* b_sp     = (const float*)d_in[3];
    const float* w_t      = (const float*)d_in[4];
    const float* b_t      = (const float*)d_in[5];
    const float* alpha    = (const float*)d_in[6];
    float* out = (float*)d_out;

    unsigned short* yT = (unsigned short*)d_ws;                       // 102,760,448 B
    short* wA  = (short*)((char*)d_ws + 102760448);                   //    294,912 B
    short* wAt = (short*)((char*)d_ws + 102760448 + 294912);          //     98,304 B

    repack_wsp<<<576, 256, 0, stream>>>(w_sp, wA);
    repack_wt2<<<192, 256, 0, stream>>>(w_t, wAt);
    spatial_mfma<<<dim3(8, 512), 256, 0, stream>>>(x, wA, b_sp, yT);
    temporal_mfma<<<dim3(7, 512), 256, 0, stream>>>(yT, wAt, b_t, alpha, x, vid_lens, out);
    write_lens<<<1, 64, 0, stream>>>(vid_lens, out);
}

// Round 8
// 336.625 us; speedup vs baseline: 1.0142x; 1.0142x over previous
//
#include <hip/hip_runtime.h>

#define TT   512
#define CH   128
#define HWP  784        // 28*28
#define NSEG 8
#define NOUT 51380224   // 512*128*784

typedef short bf16x8  __attribute__((ext_vector_type(8)));
typedef float f32x4   __attribute__((ext_vector_type(4)));
typedef float f32x16  __attribute__((ext_vector_type(16)));
typedef int   i32x4   __attribute__((ext_vector_type(4)));
typedef unsigned short u16x4 __attribute__((ext_vector_type(4)));
typedef unsigned short u16x8 __attribute__((ext_vector_type(8)));

__device__ inline unsigned short f2bf(float f) {
    unsigned u = __builtin_bit_cast(unsigned, f);
    u += 0x7fffu + ((u >> 16) & 1u);          // RNE
    return (unsigned short)(u >> 16);
}

__device__ inline void gld_lds16(const void* g, void* l) {
    __builtin_amdgcn_global_load_lds(
        (const __attribute__((address_space(1))) void*)g,
        (__attribute__((address_space(3))) void*)l, 16, 0, 0);
}

#define MFMA32(A, B, C) __builtin_amdgcn_mfma_f32_32x32x16_bf16(A, B, C, 0, 0, 0)

// ---------------------------------------------------------------------------
// Spatial weight repack for 32x32x16 MFMA, frag-major:
// frag f = tap*8+ks, block m: lane l = kgrp*32 + (co&31), elem e: ci = ks*16+kgrp*8+e
// dst = ((f*4 + m)*64 + l)*8 + e
// ---------------------------------------------------------------------------
__global__ void repack_wsp(const float* __restrict__ w, short* __restrict__ wA) {
    int s = blockIdx.x * 256 + threadIdx.x;
    if (s >= 128 * 128 * 9) return;
    int co = s / 1152, r = s % 1152, ci = r / 9, kh = (r % 9) / 3, kw = r % 3;
    int tap = kh * 3 + kw;
    int m = co >> 5, row = co & 31;
    int ks = ci >> 4, kgrp = (ci >> 3) & 1, e = ci & 7;
    int lane = kgrp * 32 + row;
    int dst = (((tap * 8 + ks) * 4 + m) * 64 + lane) * 8 + e;
    wA[dst] = (short)f2bf(w[s]);
}

// ---------------------------------------------------------------------------
// Temporal weight repack (identity ci order, 16x16x32 frag-major):
// wAt[tap][o>>4][i>>5][(i>>3)&3][o&15][i&7]
// ---------------------------------------------------------------------------
__global__ void repack_wt2(const float* __restrict__ w, short* __restrict__ wAt) {
    int s = blockIdx.x * 256 + threadIdx.x;
    if (s >= 128 * 128 * 3) return;
    int o = s / 384, r = s % 384, i = r / 3, tap = r % 3;
    int dst = tap * 16384 + (o >> 4) * 2048 + (i >> 5) * 512 +
              ((i >> 3) & 3) * 128 + (o & 15) * 8 + (i & 7);
    wAt[dst] = (short)f2bf(w[s]);
}

// ---------------------------------------------------------------------------
// Spatial 3x3 conv via mfma_f32_32x32x16_bf16. grid (4, 512), block 256.
// Block: 8 output rows x 128 co, 10-row LDS window [10][30 st][128 ci] bf16,
// slot swizzle slot' = slot ^ (st&15). Waves: ch(2 co-halves) x pg(2), wave =
// 64 co x 128 px (4 tiles of 32), acc[2][4]. Per tap: 16-frag A register
// batch (one L2 round-trip per tap, 16-deep MLP), then 8 ks x {4 B ds_reads,
// 8 MFMAs}. Epilogue: acc -> LDS bounce -> 128B-contiguous u16x8 stores.
// ---------------------------------------------------------------------------
__global__ __launch_bounds__(256, 2) void spatial_mfma(
    const float* __restrict__ x, const short* __restrict__ wA,
    const float* __restrict__ b_sp, unsigned short* __restrict__ yT)
{
    __shared__ __align__(16) short xs[300 * 128];   // 76800 B
    char* xsb = (char*)xs;
    const int t = blockIdx.y;
    const int r0 = blockIdx.x * 8;
    const int rows = (28 - r0 < 8) ? (28 - r0) : 8;
    const int pxcnt = rows * 28;
    const int tid = threadIdx.x;

    // ---- stage 10-row window, conflict-free writes (lane = ci-pair) ----
    for (int u = tid; u < 4480; u += 256) {
        int cp = u & 63, q = u >> 6;         // q 0..69
        int rl = q / 7, g = q % 7;
        int rr = r0 - 1 + rl;
        float4 f0 = make_float4(0.f, 0.f, 0.f, 0.f), f1 = f0;
        if (rr >= 0 && rr < 28) {
            const float* px0 = &x[((size_t)(t * CH + 2 * cp)) * HWP + rr * 28 + g * 4];
            f0 = *(const float4*)px0;
            f1 = *(const float4*)(px0 + HWP);
        }
        float a0[4] = {f0.x, f0.y, f0.z, f0.w}, a1[4] = {f1.x, f1.y, f1.z, f1.w};
        int stb = rl * 30 + g * 4 + 1;
#pragma unroll
        for (int j = 0; j < 4; ++j) {
            int st = stb + j;
            unsigned val = (unsigned)f2bf(a0[j]) | ((unsigned)f2bf(a1[j]) << 16);
            int addr = (st << 8) | (((cp >> 2) ^ (st & 15)) << 4) | ((cp & 3) << 2);
            *(unsigned*)(xsb + addr) = val;
        }
    }
    // ---- zero pad columns: st = r*30 + {0,29}, r = 0..9 ----
    for (int v = tid; v < 1280; v += 256) {
        int cp = v & 63, k = v >> 6;         // k 0..19
        int st = (k >> 1) * 30 + (k & 1) * 29;
        int addr = (st << 8) | (((cp >> 2) ^ (st & 15)) << 4) | ((cp & 3) << 2);
        *(unsigned*)(xsb + addr) = 0u;
    }
    __syncthreads();

    const int wid = tid >> 6, l = tid & 63;
    const int l31 = l & 31, bb5 = l >> 5;
    const int ch = wid & 1, pg = wid >> 1;
    const int ch2 = ch * 2;

    int st0[4];
#pragma unroll
    for (int ti = 0; ti < 4; ++ti) {
        int p = (pg * 4 + ti) * 32 + l31;
        int pc = (p < pxcnt) ? p : 0;        // clamp dead lanes/tiles
        st0[ti] = (pc / 28 + 1) * 30 + pc % 28 + 1;
    }

    f32x16 zz = {};
    f32x16 acc[2][4];
#pragma unroll
    for (int mi = 0; mi < 2; ++mi)
#pragma unroll
        for (int ti = 0; ti < 4; ++ti) acc[mi][ti] = zz;

    const bf16x8* wv = (const bf16x8*)wA;

    for (int tap = 0; tap < 9; ++tap) {
        const int off = (tap / 3 - 1) * 30 + (tap % 3) - 1;
        int rb[4], sw[4];
#pragma unroll
        for (int ti = 0; ti < 4; ++ti) {
            int stv = st0[ti] + off;
            rb[ti] = stv << 8;
            sw[ti] = stv & 15;
        }
        // ---- A batch: 16 independent coalesced loads (one per ks x m) ----
        bf16x8 A[16];
#pragma unroll
        for (int k2 = 0; k2 < 16; ++k2)
            A[k2] = wv[((tap * 8 + (k2 >> 1)) * 4 + ch2 + (k2 & 1)) * 64 + l];

#pragma unroll
        for (int ks = 0; ks < 8; ++ks) {
            i32x4 b[4];
#pragma unroll
            for (int ti = 0; ti < 4; ++ti)
                b[ti] = *(const i32x4*)(xsb + (rb[ti] | (((2 * ks + bb5) ^ sw[ti]) << 4)));
            __builtin_amdgcn_s_setprio(1);
#pragma unroll
            for (int ti = 0; ti < 4; ++ti) {
                bf16x8 bf = __builtin_bit_cast(bf16x8, b[ti]);
                acc[0][ti] = MFMA32(A[ks * 2], bf, acc[0][ti]);
                acc[1][ti] = MFMA32(A[ks * 2 + 1], bf, acc[1][ti]);
            }
            __builtin_amdgcn_s_setprio(0);
        }
    }

    // ---- epilogue: window dead; bounce acc through LDS for contiguity ----
    __syncthreads();
    const int wbase = wid * 17408;            // 4 tiles x 32 px x 136 B
#pragma unroll
    for (int ti = 0; ti < 4; ++ti) {
#pragma unroll
        for (int mi = 0; mi < 2; ++mi) {
#pragma unroll
            for (int r2 = 0; r2 < 4; ++r2) {
                int cb = (ch2 + mi) * 32 + 8 * r2 + 4 * bb5;
                float4 bs = *(const float4*)&b_sp[cb];
                float bsa[4] = {bs.x, bs.y, bs.z, bs.w};
                u16x4 k;
#pragma unroll
                for (int q = 0; q < 4; ++q)
                    k[q] = f2bf(acc[mi][ti][r2 * 4 + q] + bsa[q]);
                int co_off = (mi * 32 + 8 * r2 + 4 * bb5) * 2;   // within 64-ch half
                *(u16x4*)(xsb + wbase + ti * 4352 + l31 * 136 + co_off) = k;
            }
        }
    }
    // wave-private region: compiler inserts lgkmcnt before dependent reads
#pragma unroll
    for (int ti = 0; ti < 4; ++ti) {
        int tI = pg * 4 + ti;
#pragma unroll
        for (int j = 0; j < 4; ++j) {
            int idx = j * 64 + l;
            int pxl = idx >> 3, sub = idx & 7;
            u16x8 v = *(const u16x8*)(xsb + wbase + ti * 4352 + pxl * 136 + sub * 16);
            int p = tI * 32 + pxl;
            if (p < pxcnt) {
                char* dst = (char*)yT + ((size_t)t * HWP + r0 * 28 + p) * 256 +
                            ch * 128 + sub * 16;
                *(u16x8*)dst = v;
            }
        }
    }
}

// ---------------------------------------------------------------------------
// Ragged temporal conv: 4-wave blocks, async LDS-staged B, double-buffered.
// grid (7, 512), block 256. (unchanged — near HBM roofline)
// ---------------------------------------------------------------------------
__global__ __launch_bounds__(256, 4) void temporal_mfma(
    const unsigned short* __restrict__ yT, const short* __restrict__ wAt,
    const float* __restrict__ b_t, const float* __restrict__ alpha,
    const float* __restrict__ x, const int* __restrict__ vid_lens,
    float* __restrict__ out)
{
    __shared__ __align__(16) char ldsT[29696];   // 2x14336 stage | 4x7424 epi

    const int chunk = blockIdx.x, t = blockIdx.y;
    const int tid = threadIdx.x, wid = tid >> 6, l = tid & 63;
    const int l15 = l & 15, kgrp = l >> 4;
    const int sx = l15 & 7;

    bool isS = false, isE = false;
    {
        int cum = 0;
        for (int s = 0; s < NSEG; ++s) {
            if (t == cum) isS = true;
            cum += vid_lens[s];
            if (t == cum - 1) isE = true;
        }
    }
    const bool tapAct[3] = {!isS, true, !isE};

    auto stage = [&](int s) {
        int tap = s >> 1, kp = s & 1;
        if (!tapAct[tap]) return;
        int tp = t + tap - 1;
        const char* yb = (const char*)yT + (size_t)tp * HWP * 256;
        char* buf = ldsT + (s & 1) * 14336;
#pragma unroll
        for (int r = 0; r < 4; ++r) {
            int c = r * 256 + wid * 64 + l;
            if (r < 3 || wid < 2) {                    // c < 896, wave-uniform
                int px = c >> 3, sp = c & 7;
                int ssrc = sp ^ (px & 7);
                const char* g = yb + ((size_t)(chunk * 112 + px)) * 256 + kp * 128 + ssrc * 16;
                char* ldst = buf + (r * 256 + wid * 64) * 16;
                gld_lds16(g, ldst);
            }
        }
    };

    f32x4 acc[2][7];
#pragma unroll
    for (int m = 0; m < 2; ++m)
#pragma unroll
        for (int n = 0; n < 7; ++n) acc[m][n] = (f32x4){0.f, 0.f, 0.f, 0.f};

    const bf16x8* wAv = (const bf16x8*)wAt;

    stage(0);
    __syncthreads();

    for (int s = 0; s < 6; ++s) {
        if (s < 5) stage(s + 1);
        int tap = s >> 1, kp = s & 1;
        if (tapAct[tap]) {
            const char* buf = ldsT + (s & 1) * 14336;
            bf16x8 a[2][2];
#pragma unroll
            for (int m = 0; m < 2; ++m)
#pragma unroll
                for (int k1 = 0; k1 < 2; ++k1)
                    a[m][k1] = wAv[((tap * 8 + wid * 2 + m) * 4 + kp * 2 + k1) * 64 + l];
            __builtin_amdgcn_s_setprio(1);
#pragma unroll
            for (int k1 = 0; k1 < 2; ++k1) {
#pragma unroll
                for (int nf = 0; nf < 7; ++nf) {
                    int addr = (nf * 16 + l15) * 128 + ((k1 * 4 + kgrp) ^ sx) * 16;
                    i32x4 bi = *(const i32x4*)(buf + addr);
                    bf16x8 b = __builtin_bit_cast(bf16x8, bi);
                    acc[0][nf] = __builtin_amdgcn_mfma_f32_16x16x32_bf16(a[0][k1], b, acc[0][nf], 0, 0, 0);
                    acc[1][nf] = __builtin_amdgcn_mfma_f32_16x16x32_bf16(a[1][k1], b, acc[1][nf], 0, 0, 0);
                }
            }
            __builtin_amdgcn_s_setprio(0);
        }
        __syncthreads();
    }

    // ---- epilogue: LDS transpose -> coalesced bias/PReLU/residual/store ----
    float* fl = (float*)ldsT;
    const int wbase = wid * 1856;            // 16 co x 116 px-stride floats
#pragma unroll
    for (int m = 0; m < 2; ++m) {
#pragma unroll
        for (int nf = 0; nf < 7; ++nf)
#pragma unroll
            for (int rr = 0; rr < 4; ++rr)
                fl[wbase + (kgrp * 4 + rr) * 116 + nf * 16 + l15] = acc[m][nf][rr];
#pragma unroll
        for (int j = 0; j < 7; ++j) {
            int idx = j * 64 + l;
            int co_r = idx / 28, q = idx % 28;
            f32x4 v4 = *(const f32x4*)&fl[wbase + co_r * 116 + q * 4];
            int co_g = wid * 32 + m * 16 + co_r;
            float bt = b_t[co_g], al = alpha[co_g];
            size_t gi = ((size_t)(t * CH + co_g)) * HWP + chunk * 112 + q * 4;
            float4 xv = *(const float4*)&x[gi];
            float xr[4] = {xv.x, xv.y, xv.z, xv.w};
            float rrv[4];
#pragma unroll
            for (int e = 0; e < 4; ++e) {
                float v = v4[e] + bt;
                v = (v >= 0.f) ? v : al * v;
                rrv[e] = v + xr[e];
            }
            *(float4*)&out[gi] = make_float4(rrv[0], rrv[1], rrv[2], rrv[3]);
        }
        __syncthreads();   // all waves done with region before m=1 reuse
    }
}

// ---------------------------------------------------------------------------
__global__ void write_lens(const int* __restrict__ vid_lens, float* __restrict__ out) {
    int i = threadIdx.x;
    if (i < NSEG) out[NOUT + i] = (float)vid_lens[i];
}

// ---------------------------------------------------------------------------
extern "C" void kernel_launch(void* const* d_in, const int* in_sizes, int n_in,
                              void* d_out, int out_size, void* d_ws, size_t ws_size,
                              hipStream_t stream) {
    const float* x        = (const float*)d_in[0];
    const int*   vid_lens = (const int*)d_in[1];
    const float* w_sp     = (const float*)d_in[2];
    const float* b_sp     = (const float*)d_in[3];
    const float* w_t      = (const float*)d_in[4];
    const float* b_t      = (const float*)d_in[5];
    const float* alpha    = (const float*)d_in[6];
    float* out = (float*)d_out;

    unsigned short* yT = (unsigned short*)d_ws;                       // 102,760,448 B
    short* wA  = (short*)((char*)d_ws + 102760448);                   //    294,912 B
    short* wAt = (short*)((char*)d_ws + 102760448 + 294912);          //     98,304 B

    repack_wsp<<<576, 256, 0, stream>>>(w_sp, wA);
    repack_wt2<<<192, 256, 0, stream>>>(w_t, wAt);
    spatial_mfma<<<dim3(4, 512), 256, 0, stream>>>(x, wA, b_sp, yT);
    temporal_mfma<<<dim3(7, 512), 256, 0, stream>>>(yT, wAt, b_t, alpha, x, vid_lens, out);
    write_lens<<<1, 64, 0, stream>>>(vid_lens, out);
}